// Round 5
// baseline (297.724 us; speedup 1.0000x reference)
//
#include <hip/hip_runtime.h>
#include <cstddef>

// N=16384, D=256, V=32000, T=128, decay=0.97
namespace {
constexpr int Nn = 16384;
constexpr int Dd = 256;
constexpr int Tt = 128;
constexpr float DECAY = 0.97f;

// workspace layout (float offsets)
constexpr size_t WS_CUMVT = 0;      // u16 cumVT[d][s] [256][128]  (16384 f)
constexpr size_t WS_VB    = 16384;  // f32 Vb[t][d]    [128][256]  (32768 f)
constexpr size_t WS_VBBF  = 49152;  // u16 VbBf[t][d]  [128][256]  (16384 f)
constexpr size_t WS_H     = 65536;  // f32 h[s]        [128]
constexpr size_t WS_U     = 65664;  // f32 u[d]        [256]
}

typedef __attribute__((ext_vector_type(8))) short short8;
typedef __attribute__((ext_vector_type(4))) short short4v;
typedef __attribute__((ext_vector_type(4))) float f32x4;
typedef __attribute__((ext_vector_type(4))) unsigned int u32x4;
typedef unsigned short u16;

__device__ __forceinline__ u16 f2bf(float f) {  // RNE f32->bf16
  unsigned u = __builtin_bit_cast(unsigned, f);
  return (u16)((u + 0x7fffu + ((u >> 16) & 1u)) >> 16);
}

// ---------------------------------------------------------------------------
// K0a: parallel gather: Vb[s][d] = temb[toks[s]][d] (f32 + bf16 copies)
__global__ __launch_bounds__(256) void k_gather(const float* __restrict__ temb,
                                                const int* __restrict__ toks,
                                                float* __restrict__ Vb,
                                                u16* __restrict__ VbBf) {
  const int s = blockIdx.x, d = threadIdx.x;
  float v = temb[(size_t)toks[s] * Dd + d];
  Vb[s * Dd + d] = v;
  VbBf[s * Dd + d] = f2bf(v);
}

// K0b: 1 block: suffix scan cumVT[d][s] = bf16(sum_{t>=s} 0.97^(128-t) V[t][d]).
// Fully unrolled -> 128 independent L2/L3-hot loads in flight; row accumulated
// in registers (static indexing), written as 16 float4 stores per thread.
__global__ __launch_bounds__(256) void k_cumv(const float* __restrict__ Vb,
                                              u16* __restrict__ cumVT) {
  const int d = threadIdx.x;
  float run = 0.f, w = DECAY;
  unsigned pk[64];
#pragma unroll
  for (int t = Tt - 1; t >= 0; --t) {
    run += w * Vb[t * Dd + d];  // coalesced across lanes; independent per t
    w *= DECAY;
    unsigned bb = (unsigned)f2bf(run);
    if (t & 1) pk[t >> 1] = bb << 16;  // odd t processed first (descending)
    else       pk[t >> 1] |= bb;       // low half = even s (little-endian)
  }
#pragma unroll
  for (int i = 0; i < 16; ++i) {
    u32x4 o = {pk[4 * i], pk[4 * i + 1], pk[4 * i + 2], pk[4 * i + 3]};
    *(u32x4*)&cumVT[d * Tt + i * 8] = o;
  }
}

// ---------------------------------------------------------------------------
// K1: per block (512): M rows [j0,j0+32) x all 128 t via bf16 MFMA;
//     relu in f32 accs; xf row-sums + h[s] partials from registers;
//     M tile -> LDS bf16; then rho[:, j0..j0+32) = cumVT x M^T (MFMA).
// MFMA 16x16x32 frag layout: A row=lane&15, k=(lane>>4)*8+{0..7};
//                            B col=lane&15, k likewise;
//                            D col=lane&15, row=(lane>>4)*4+reg  [m89/m92].
__global__ __launch_bounds__(256) void k_p1(const float* __restrict__ Dx,
                                            const u16* __restrict__ VbBf,
                                            const u16* __restrict__ cumVT,
                                            float* __restrict__ h,
                                            float* __restrict__ xf,
                                            float* __restrict__ rho) {
  // LDS (frag rows padded to odd multiples of 16B: 80B / 272B strides)
  __shared__ __align__(16) u16 Asl[32 * 40];    // Dx tile [32 j][32 k]
  __shared__ __align__(16) u16 Bsl[128 * 40];   // V^T tile [128 t][32 k]
  __shared__ __align__(16) u16 Mld[32 * 136];   // M tile [32 j][128 s]
  __shared__ __align__(16) u16 CVl[64 * 136];   // cumVT chunk [64 d][128 s]
  __shared__ float xpart[4][16];
  __shared__ float hpart[4][64];
  __shared__ float xjl[32];

  const int tid = threadIdx.x;
  const int j0 = blockIdx.x * 32;
  const int w = tid >> 6, l = tid & 63;
  const int jt = w & 1, thf = w >> 1;     // wave: j-tile, t-half
  const int lr = l & 15, lg = l >> 4;

  const float4* Dx4 = (const float4*)Dx;    // row stride 64 f4
  const float4* VB4 = (const float4*)VbBf;  // row stride 32 f4 (bf16)

  const int ar = tid >> 3, akq = tid & 7;  // A stage: row, f4 slot
  const int btr = tid >> 1, bh = tid & 1;  // B stage: t row, k half

  f32x4 zero = {0.f, 0.f, 0.f, 0.f};
  f32x4 acc[4] = {zero, zero, zero, zero};

  float4 pa = Dx4[(size_t)(j0 + ar) * 64 + akq];
  float4 pb0 = VB4[btr * 32 + bh * 2];
  float4 pb1 = VB4[btr * 32 + bh * 2 + 1];

  for (int ch = 0; ch < 8; ++ch) {
    __syncthreads();
    {  // A: 4 bf16 (8B) at [ar][akq*4], converted f32->bf16 (unique data)
      short4v a4;
      a4[0] = (short)f2bf(pa.x); a4[1] = (short)f2bf(pa.y);
      a4[2] = (short)f2bf(pa.z); a4[3] = (short)f2bf(pa.w);
      *(short4v*)&Asl[ar * 40 + akq * 4] = a4;
    }
    // B: plain 32B copy (pre-converted bf16)
    *(float4*)&Bsl[btr * 40 + bh * 16] = pb0;
    *(float4*)&Bsl[btr * 40 + bh * 16 + 8] = pb1;
    __syncthreads();
    if (ch < 7) {  // register prefetch; hides under MFMAs
      pa = Dx4[(size_t)(j0 + ar) * 64 + (ch + 1) * 8 + akq];
      pb0 = VB4[btr * 32 + (ch + 1) * 4 + bh * 2];
      pb1 = VB4[btr * 32 + (ch + 1) * 4 + bh * 2 + 1];
    }
    short8 av = *(const short8*)&Asl[(jt * 16 + lr) * 40 + lg * 8];
#pragma unroll
    for (int tt = 0; tt < 4; ++tt) {
      short8 bv = *(const short8*)&Bsl[((thf * 4 + tt) * 16 + lr) * 40 + lg * 8];
      acc[tt] = __builtin_amdgcn_mfma_f32_16x16x32_bf16(av, bv, acc[tt], 0, 0, 0);
    }
  }

  // relu + M tile to LDS (bf16). acc elem (tt,q): j_loc = jt*16+lg*4+q,
  // t = thf*64 + tt*16 + lr
#pragma unroll
  for (int tt = 0; tt < 4; ++tt)
#pragma unroll
    for (int q = 0; q < 4; ++q) {
      float vv = fmaxf(acc[tt][q], 0.f);
      acc[tt][q] = vv;
      Mld[(jt * 16 + lg * 4 + q) * 136 + thf * 64 + tt * 16 + lr] = f2bf(vv);
    }

  // xf: row sums (reduce over this wave's 16 t-cols, then partner wave)
  float p0 = acc[0][0] + acc[1][0] + acc[2][0] + acc[3][0];
  float p1 = acc[0][1] + acc[1][1] + acc[2][1] + acc[3][1];
  float p2 = acc[0][2] + acc[1][2] + acc[2][2] + acc[3][2];
  float p3 = acc[0][3] + acc[1][3] + acc[2][3] + acc[3][3];
#pragma unroll
  for (int m = 1; m <= 8; m <<= 1) {
    p0 += __shfl_xor(p0, m); p1 += __shfl_xor(p1, m);
    p2 += __shfl_xor(p2, m); p3 += __shfl_xor(p3, m);
  }
  float pv = p0;
  if (lr == 1) pv = p1; else if (lr == 2) pv = p2; else if (lr == 3) pv = p3;
  if (lr < 4) xpart[w][lg * 4 + lr] = pv;
  __syncthreads();
  if (tid < 32) {
    float s = xpart[tid >> 4][tid & 15] + xpart[(tid >> 4) + 2][tid & 15];
    xjl[tid] = s;
    xf[j0 + tid] = s;  // x_{T-1}
  }
  __syncthreads();

  // h[t] partials: sum_j M[j][t]*xf[j] over this block's 32 rows
  float xq0 = xjl[jt * 16 + lg * 4 + 0];
  float xq1 = xjl[jt * 16 + lg * 4 + 1];
  float xq2 = xjl[jt * 16 + lg * 4 + 2];
  float xq3 = xjl[jt * 16 + lg * 4 + 3];
  float ph0 = acc[0][0]*xq0 + acc[0][1]*xq1 + acc[0][2]*xq2 + acc[0][3]*xq3;
  float ph1 = acc[1][0]*xq0 + acc[1][1]*xq1 + acc[1][2]*xq2 + acc[1][3]*xq3;
  float ph2 = acc[2][0]*xq0 + acc[2][1]*xq1 + acc[2][2]*xq2 + acc[2][3]*xq3;
  float ph3 = acc[3][0]*xq0 + acc[3][1]*xq1 + acc[3][2]*xq2 + acc[3][3]*xq3;
#pragma unroll
  for (int m = 16; m <= 32; m <<= 1) {
    ph0 += __shfl_xor(ph0, m); ph1 += __shfl_xor(ph1, m);
    ph2 += __shfl_xor(ph2, m); ph3 += __shfl_xor(ph3, m);
  }
  if (l < 16) {
    hpart[w][l] = ph0; hpart[w][16 + l] = ph1;
    hpart[w][32 + l] = ph2; hpart[w][48 + l] = ph3;
  }
  __syncthreads();
  if (tid < Tt) {
    int half = tid >> 6;
    atomicAdd(&h[tid], hpart[half * 2][tid & 63] + hpart[half * 2 + 1][tid & 63]);
  }

  // ---- rho phase: rho[d][j0+jl] = sum_s cumVT[d][s] * M[jl][s] ----
  const float4* CV4 = (const float4*)cumVT;  // 16B = 8 bf16
  float4 q0 = CV4[tid], q1 = CV4[tid + 256], q2 = CV4[tid + 512],
         q3 = CV4[tid + 768];
  for (int dc = 0; dc < 4; ++dc) {
    __syncthreads();
    *(float4*)&CVl[(tid >> 4) * 136 + (tid & 15) * 8] = q0;
    *(float4*)&CVl[((tid + 256) >> 4) * 136 + (tid & 15) * 8] = q1;
    *(float4*)&CVl[((tid + 512) >> 4) * 136 + (tid & 15) * 8] = q2;
    *(float4*)&CVl[((tid + 768) >> 4) * 136 + (tid & 15) * 8] = q3;
    __syncthreads();
    if (dc < 3) {
      q0 = CV4[(dc + 1) * 1024 + tid];
      q1 = CV4[(dc + 1) * 1024 + tid + 256];
      q2 = CV4[(dc + 1) * 1024 + tid + 512];
      q3 = CV4[(dc + 1) * 1024 + tid + 768];
    }
    f32x4 r0 = zero, r1 = zero;
#pragma unroll
    for (int ks = 0; ks < 4; ++ks) {
      short8 a = *(const short8*)&CVl[(w * 16 + lr) * 136 + ks * 32 + lg * 8];
      short8 b0 = *(const short8*)&Mld[lr * 136 + ks * 32 + lg * 8];
      short8 b1 = *(const short8*)&Mld[(16 + lr) * 136 + ks * 32 + lg * 8];
      r0 = __builtin_amdgcn_mfma_f32_16x16x32_bf16(a, b0, r0, 0, 0, 0);
      r1 = __builtin_amdgcn_mfma_f32_16x16x32_bf16(a, b1, r1, 0, 0, 0);
    }
#pragma unroll
    for (int q = 0; q < 4; ++q) {
      size_t drow = (size_t)(dc * 64 + w * 16 + lg * 4 + q) * Nn;
      rho[drow + j0 + lr] = r0[q];
      rho[drow + j0 + 16 + lr] = r1[q];
    }
  }
}

// ---------------------------------------------------------------------------
// K2 (fused): per block (256): redundant {scan h -> g, a_star, LN -> lna};
// then y rows [b*64, b*64+64); then u[d] partials over this block's E columns.
__global__ __launch_bounds__(256) void k_yu(const float* __restrict__ Dy,
                                            const float* __restrict__ E,
                                            const float* __restrict__ Vb,
                                            const float* __restrict__ h,
                                            const float* __restrict__ xf,
                                            float* __restrict__ yv,
                                            float* __restrict__ u) {
  __shared__ float g[Tt];
  __shared__ float red[Dd];
  __shared__ float lna_l[Dd];
  __shared__ float y_l[64];
  const int tid = threadIdx.x;
  const int b = blockIdx.x;
  const int wv = tid >> 6, lane = tid & 63;
  const int j0 = b * 64;

  if (tid < Tt) g[tid] = h[tid];
  __syncthreads();
  for (int off = 1; off < Tt; off <<= 1) {  // inclusive scan: g[t]=x_t.x_{T-1}
    float vsc = 0.f;
    bool act = (tid < Tt) && (tid >= off);
    if (act) vsc = g[tid - off];
    __syncthreads();
    if (act) g[tid] += vsc;
    __syncthreads();
  }
  float a = 0.f, w = DECAY;
  for (int t = Tt - 2; t >= 0; --t) {
    a += w * g[t] * Vb[t * Dd + tid];
    w *= DECAY;
  }
  red[tid] = a;
  __syncthreads();
  for (int off = 128; off > 0; off >>= 1) {
    if (tid < off) red[tid] += red[tid + off];
    __syncthreads();
  }
  float m = red[0] * (1.f / 256.f);
  __syncthreads();
  float c0 = a - m;
  red[tid] = c0 * c0;
  __syncthreads();
  for (int off = 128; off > 0; off >>= 1) {
    if (tid < off) red[tid] += red[tid + off];
    __syncthreads();
  }
  float sd = sqrtf(red[0] * (1.f / 255.f));
  lna_l[tid] = c0 / (sd + 1e-6f);
  __syncthreads();

  // y phase: wave wv handles rows [wv*16, wv*16+16)
  const float4* Dy4 = (const float4*)Dy;
  const float4* l4 = (const float4*)lna_l;
  float4 lv = l4[lane];
  for (int i = 0; i < 16; ++i) {
    int jl = wv * 16 + i, j = j0 + jl;
    float4 dv = Dy4[(size_t)j * 64 + lane];
    float accy = dv.x * lv.x + dv.y * lv.y + dv.z * lv.z + dv.w * lv.w;
#pragma unroll
    for (int off = 32; off > 0; off >>= 1) accy += __shfl_down(accy, off);
    float xv = xf[j];
    if (lane == 0) {
      float yy = fmaxf(accy, 0.f) * fmaxf(xv, 0.f);
      y_l[jl] = yy;
      yv[j] = yy;
    }
  }
  __syncthreads();

  // u partials: u[d] += E[d][j0..j0+64) . y_l  (coalesced 256B rows)
  float yj = y_l[lane];
  for (int i = 0; i < 64; ++i) {
    int d = wv * 64 + i;
    float p = E[(size_t)d * Nn + j0 + lane] * yj;
#pragma unroll
    for (int off = 32; off > 0; off >>= 1) p += __shfl_down(p, off);
    if (lane == 0) atomicAdd(&u[d], p);
  }
}

// K3: v_star = ln_row(u)
__global__ void k_v(const float* __restrict__ u, float* __restrict__ vout) {
  __shared__ float red[256];
  const int d = threadIdx.x;
  float a = u[d];
  red[d] = a;
  __syncthreads();
  for (int off = 128; off > 0; off >>= 1) {
    if (d < off) red[d] += red[d + off];
    __syncthreads();
  }
  float m = red[0] * (1.f / 256.f);
  __syncthreads();
  float c0 = a - m;
  red[d] = c0 * c0;
  __syncthreads();
  for (int off = 128; off > 0; off >>= 1) {
    if (d < off) red[d] += red[d + off];
    __syncthreads();
  }
  float sd = sqrtf(red[0] * (1.f / 255.f));
  vout[d] = c0 / (sd + 1e-6f);
}

// ---------------------------------------------------------------------------
extern "C" void kernel_launch(void* const* d_in, const int* in_sizes, int n_in,
                              void* d_out, int out_size, void* d_ws, size_t ws_size,
                              hipStream_t stream) {
  const float* E = (const float*)d_in[0];     // [256][16384]
  const float* Dx = (const float*)d_in[1];    // [16384][256]
  const float* Dy = (const float*)d_in[2];    // [16384][256]
  const float* temb = (const float*)d_in[3];  // [32000][256]
  const int* toks = (const int*)d_in[4];      // [128]

  float* ws = (float*)d_ws;
  float* out = (float*)d_out;
  u16* cumVT = (u16*)(ws + WS_CUMVT);
  float* Vb  = ws + WS_VB;
  u16* VbBf  = (u16*)(ws + WS_VBBF);
  float* h   = ws + WS_H;
  float* u   = ws + WS_U;

  float* xf  = out;                // x_{T-1}   [16384]
  float* yv  = out + Nn;           // ys[-1]    [16384]
  float* vs  = out + 2 * Nn;       // vs[-1]    [256]
  float* rho = out + 2 * Nn + Dd;  // rho_f     [256][16384]

  hipMemsetAsync(h, 0, (Tt + Dd) * sizeof(float), stream);  // h, u

  k_gather<<<Tt, Dd, 0, stream>>>(temb, toks, Vb, VbBf);
  k_cumv<<<1, Dd, 0, stream>>>(Vb, cumVT);
  k_p1<<<Nn / 32, 256, 0, stream>>>(Dx, VbBf, cumVT, h, xf, rho);
  k_yu<<<Nn / 64, 256, 0, stream>>>(Dy, E, Vb, h, xf, yv, u);
  k_v<<<1, 256, 0, stream>>>(u, vs);
}

// Round 6
// 156.180 us; speedup vs baseline: 1.9063x; 1.9063x over previous
//
#include <hip/hip_runtime.h>
#include <cstddef>

// N=16384, D=256, V=32000, T=128, decay=0.97
namespace {
constexpr int Nn = 16384;
constexpr int Dd = 256;
constexpr int Tt = 128;
constexpr float DECAY = 0.97f;

// workspace layout (float offsets)
constexpr size_t WS_CUMVT = 0;      // u16 cumVT[d][s] [256][128]  (16384 f)
constexpr size_t WS_VB    = 16384;  // f32 Vb[t][d]    [128][256]  (32768 f)
constexpr size_t WS_VBBF  = 49152;  // u16 VbBf[t][d]  [128][256]  (16384 f)
constexpr size_t WS_H     = 65536;  // f32 h[s]        [128]
constexpr size_t WS_U     = 65664;  // f32 u[d]        [256]
constexpr size_t WS_LNA   = 65920;  // f32 lna[d]      [256]
}

typedef __attribute__((ext_vector_type(8))) short short8;
typedef __attribute__((ext_vector_type(4))) short short4v;
typedef __attribute__((ext_vector_type(4))) float f32x4;
typedef __attribute__((ext_vector_type(4))) unsigned int u32x4;
typedef unsigned short u16;

__device__ __forceinline__ u16 f2bf(float f) {  // RNE f32->bf16
  unsigned u = __builtin_bit_cast(unsigned, f);
  return (u16)((u + 0x7fffu + ((u >> 16) & 1u)) >> 16);
}

// ---------------------------------------------------------------------------
// K0a: parallel gather: Vb[s][d] = temb[toks[s]][d] (f32 + bf16 copies)
__global__ __launch_bounds__(256) void k_gather(const float* __restrict__ temb,
                                                const int* __restrict__ toks,
                                                float* __restrict__ Vb,
                                                u16* __restrict__ VbBf) {
  const int s = blockIdx.x, d = threadIdx.x;
  float v = temb[(size_t)toks[s] * Dd + d];
  Vb[s * Dd + d] = v;
  VbBf[s * Dd + d] = f2bf(v);
}

// K0b: 1 block: suffix scan cumVT[d][s] = bf16(sum_{t>=s} 0.97^(128-t) V[t][d]).
// Fully unrolled -> independent L2-hot loads in flight; row accumulated in
// registers (static indexing), written as 16 float4 stores per thread.
__global__ __launch_bounds__(256) void k_cumv(const float* __restrict__ Vb,
                                              u16* __restrict__ cumVT) {
  const int d = threadIdx.x;
  float run = 0.f, w = DECAY;
  unsigned pk[64];
#pragma unroll
  for (int t = Tt - 1; t >= 0; --t) {
    run += w * Vb[t * Dd + d];  // coalesced across lanes; independent per t
    w *= DECAY;
    unsigned bb = (unsigned)f2bf(run);
    if (t & 1) pk[t >> 1] = bb << 16;  // odd t processed first (descending)
    else       pk[t >> 1] |= bb;       // low half = even s (little-endian)
  }
#pragma unroll
  for (int i = 0; i < 16; ++i) {
    u32x4 o = {pk[4 * i], pk[4 * i + 1], pk[4 * i + 2], pk[4 * i + 3]};
    *(u32x4*)&cumVT[d * Tt + i * 8] = o;
  }
}

// ---------------------------------------------------------------------------
// K1: per block (512): M rows [j0,j0+32) x all 128 t via bf16 MFMA;
//     relu in f32 accs; xf row-sums + h[s] partials from registers;
//     M tile -> LDS bf16; then rho[:, j0..j0+32) = cumVT x M^T (MFMA).
// MFMA 16x16x32 frag layout: A row=lane&15, k=(lane>>4)*8+{0..7};
//                            B col=lane&15, k likewise;
//                            D col=lane&15, row=(lane>>4)*4+reg  [m89/m92].
__global__ __launch_bounds__(256) void k_p1(const float* __restrict__ Dx,
                                            const u16* __restrict__ VbBf,
                                            const u16* __restrict__ cumVT,
                                            float* __restrict__ h,
                                            float* __restrict__ xf,
                                            float* __restrict__ rho) {
  // LDS (frag rows padded to odd multiples of 16B: 80B / 272B strides)
  __shared__ __align__(16) u16 Asl[32 * 40];    // Dx tile [32 j][32 k]
  __shared__ __align__(16) u16 Bsl[128 * 40];   // V^T tile [128 t][32 k]
  __shared__ __align__(16) u16 Mld[32 * 136];   // M tile [32 j][128 s]
  __shared__ __align__(16) u16 CVl[64 * 136];   // cumVT chunk [64 d][128 s]
  __shared__ float xpart[4][16];
  __shared__ float hpart[4][64];
  __shared__ float xjl[32];

  const int tid = threadIdx.x;
  const int j0 = blockIdx.x * 32;
  const int w = tid >> 6, l = tid & 63;
  const int jt = w & 1, thf = w >> 1;     // wave: j-tile, t-half
  const int lr = l & 15, lg = l >> 4;

  const float4* Dx4 = (const float4*)Dx;    // row stride 64 f4
  const float4* VB4 = (const float4*)VbBf;  // row stride 32 f4 (bf16)

  const int ar = tid >> 3, akq = tid & 7;  // A stage: row, f4 slot
  const int btr = tid >> 1, bh = tid & 1;  // B stage: t row, k half

  f32x4 zero = {0.f, 0.f, 0.f, 0.f};
  f32x4 acc[4] = {zero, zero, zero, zero};

  float4 pa = Dx4[(size_t)(j0 + ar) * 64 + akq];
  float4 pb0 = VB4[btr * 32 + bh * 2];
  float4 pb1 = VB4[btr * 32 + bh * 2 + 1];

  for (int ch = 0; ch < 8; ++ch) {
    __syncthreads();
    {  // A: 4 bf16 (8B) at [ar][akq*4], converted f32->bf16 (unique data)
      short4v a4;
      a4[0] = (short)f2bf(pa.x); a4[1] = (short)f2bf(pa.y);
      a4[2] = (short)f2bf(pa.z); a4[3] = (short)f2bf(pa.w);
      *(short4v*)&Asl[ar * 40 + akq * 4] = a4;
    }
    // B: plain 32B copy (pre-converted bf16)
    *(float4*)&Bsl[btr * 40 + bh * 16] = pb0;
    *(float4*)&Bsl[btr * 40 + bh * 16 + 8] = pb1;
    __syncthreads();
    if (ch < 7) {  // register prefetch; hides under MFMAs
      pa = Dx4[(size_t)(j0 + ar) * 64 + (ch + 1) * 8 + akq];
      pb0 = VB4[btr * 32 + (ch + 1) * 4 + bh * 2];
      pb1 = VB4[btr * 32 + (ch + 1) * 4 + bh * 2 + 1];
    }
    short8 av = *(const short8*)&Asl[(jt * 16 + lr) * 40 + lg * 8];
#pragma unroll
    for (int tt = 0; tt < 4; ++tt) {
      short8 bv = *(const short8*)&Bsl[((thf * 4 + tt) * 16 + lr) * 40 + lg * 8];
      acc[tt] = __builtin_amdgcn_mfma_f32_16x16x32_bf16(av, bv, acc[tt], 0, 0, 0);
    }
  }

  // relu + M tile to LDS (bf16). acc elem (tt,q): j_loc = jt*16+lg*4+q,
  // t = thf*64 + tt*16 + lr
#pragma unroll
  for (int tt = 0; tt < 4; ++tt)
#pragma unroll
    for (int q = 0; q < 4; ++q) {
      float vv = fmaxf(acc[tt][q], 0.f);
      acc[tt][q] = vv;
      Mld[(jt * 16 + lg * 4 + q) * 136 + thf * 64 + tt * 16 + lr] = f2bf(vv);
    }

  // xf: row sums (reduce over this wave's 16 t-cols, then partner wave)
  float p0 = acc[0][0] + acc[1][0] + acc[2][0] + acc[3][0];
  float p1 = acc[0][1] + acc[1][1] + acc[2][1] + acc[3][1];
  float p2 = acc[0][2] + acc[1][2] + acc[2][2] + acc[3][2];
  float p3 = acc[0][3] + acc[1][3] + acc[2][3] + acc[3][3];
#pragma unroll
  for (int m = 1; m <= 8; m <<= 1) {
    p0 += __shfl_xor(p0, m); p1 += __shfl_xor(p1, m);
    p2 += __shfl_xor(p2, m); p3 += __shfl_xor(p3, m);
  }
  float pv = p0;
  if (lr == 1) pv = p1; else if (lr == 2) pv = p2; else if (lr == 3) pv = p3;
  if (lr < 4) xpart[w][lg * 4 + lr] = pv;
  __syncthreads();
  if (tid < 32) {
    float s = xpart[tid >> 4][tid & 15] + xpart[(tid >> 4) + 2][tid & 15];
    xjl[tid] = s;
    xf[j0 + tid] = s;  // x_{T-1}
  }
  __syncthreads();

  // h[t] partials: sum_j M[j][t]*xf[j] over this block's 32 rows
  float xq0 = xjl[jt * 16 + lg * 4 + 0];
  float xq1 = xjl[jt * 16 + lg * 4 + 1];
  float xq2 = xjl[jt * 16 + lg * 4 + 2];
  float xq3 = xjl[jt * 16 + lg * 4 + 3];
  float ph0 = acc[0][0]*xq0 + acc[0][1]*xq1 + acc[0][2]*xq2 + acc[0][3]*xq3;
  float ph1 = acc[1][0]*xq0 + acc[1][1]*xq1 + acc[1][2]*xq2 + acc[1][3]*xq3;
  float ph2 = acc[2][0]*xq0 + acc[2][1]*xq1 + acc[2][2]*xq2 + acc[2][3]*xq3;
  float ph3 = acc[3][0]*xq0 + acc[3][1]*xq1 + acc[3][2]*xq2 + acc[3][3]*xq3;
#pragma unroll
  for (int m = 16; m <= 32; m <<= 1) {
    ph0 += __shfl_xor(ph0, m); ph1 += __shfl_xor(ph1, m);
    ph2 += __shfl_xor(ph2, m); ph3 += __shfl_xor(ph3, m);
  }
  if (l < 16) {
    hpart[w][l] = ph0; hpart[w][16 + l] = ph1;
    hpart[w][32 + l] = ph2; hpart[w][48 + l] = ph3;
  }
  __syncthreads();
  if (tid < Tt) {
    int half = tid >> 6;
    atomicAdd(&h[tid], hpart[half * 2][tid & 63] + hpart[half * 2 + 1][tid & 63]);
  }

  // ---- rho phase: rho[d][j0+jl] = sum_s cumVT[d][s] * M[jl][s] ----
  const float4* CV4 = (const float4*)cumVT;  // 16B = 8 bf16
  float4 q0 = CV4[tid], q1 = CV4[tid + 256], q2 = CV4[tid + 512],
         q3 = CV4[tid + 768];
  for (int dc = 0; dc < 4; ++dc) {
    __syncthreads();
    *(float4*)&CVl[(tid >> 4) * 136 + (tid & 15) * 8] = q0;
    *(float4*)&CVl[((tid + 256) >> 4) * 136 + (tid & 15) * 8] = q1;
    *(float4*)&CVl[((tid + 512) >> 4) * 136 + (tid & 15) * 8] = q2;
    *(float4*)&CVl[((tid + 768) >> 4) * 136 + (tid & 15) * 8] = q3;
    __syncthreads();
    if (dc < 3) {
      q0 = CV4[(dc + 1) * 1024 + tid];
      q1 = CV4[(dc + 1) * 1024 + tid + 256];
      q2 = CV4[(dc + 1) * 1024 + tid + 512];
      q3 = CV4[(dc + 1) * 1024 + tid + 768];
    }
    f32x4 r0 = zero, r1 = zero;
#pragma unroll
    for (int ks = 0; ks < 4; ++ks) {
      short8 a = *(const short8*)&CVl[(w * 16 + lr) * 136 + ks * 32 + lg * 8];
      short8 b0 = *(const short8*)&Mld[lr * 136 + ks * 32 + lg * 8];
      short8 b1 = *(const short8*)&Mld[(16 + lr) * 136 + ks * 32 + lg * 8];
      r0 = __builtin_amdgcn_mfma_f32_16x16x32_bf16(a, b0, r0, 0, 0, 0);
      r1 = __builtin_amdgcn_mfma_f32_16x16x32_bf16(a, b1, r1, 0, 0, 0);
    }
#pragma unroll
    for (int q = 0; q < 4; ++q) {
      size_t drow = (size_t)(dc * 64 + w * 16 + lg * 4 + q) * Nn;
      rho[drow + j0 + lr] = r0[q];
      rho[drow + j0 + 16 + lr] = r1[q];
    }
  }
}

// ---------------------------------------------------------------------------
// K2: g = prefix(h); a_star[d] = sum_{t<=T-2} 0.97^(T-1-t) g[t] V[t][d]; LN
__global__ __launch_bounds__(256) void k_astar(const float* __restrict__ h,
                                               const float* __restrict__ Vb,
                                               float* __restrict__ lna) {
  __shared__ float g[Tt];
  __shared__ float red[Dd];
  const int d = threadIdx.x;
  if (d < Tt) g[d] = h[d];
  __syncthreads();
  for (int off = 1; off < Tt; off <<= 1) {  // inclusive scan
    float v = 0.f;
    bool act = (d < Tt) && (d >= off);
    if (act) v = g[d - off];
    __syncthreads();
    if (act) g[d] += v;
    __syncthreads();
  }
  float a = 0.f, wv = DECAY;
  for (int t = Tt - 2; t >= 0; --t) {
    a += wv * g[t] * Vb[t * Dd + d];
    wv *= DECAY;
  }
  red[d] = a;
  __syncthreads();
  for (int off = 128; off > 0; off >>= 1) {
    if (d < off) red[d] += red[d + off];
    __syncthreads();
  }
  float m = red[0] * (1.f / 256.f);
  __syncthreads();
  float c0 = a - m;
  red[d] = c0 * c0;
  __syncthreads();
  for (int off = 128; off > 0; off >>= 1) {
    if (d < off) red[d] += red[d + off];
    __syncthreads();
  }
  float sd = sqrtf(red[0] * (1.f / 255.f));
  lna[d] = c0 / (sd + 1e-6f);
}

// ---------------------------------------------------------------------------
// K3: y[j] = relu(Dy[j].lna) * max(x[j],0)   (one wave per row; 16 blocks/CU)
__global__ void k_y(const float* __restrict__ Dy, const float* __restrict__ lna,
                    const float* __restrict__ x, float* __restrict__ yout) {
  const int tid = threadIdx.x;
  const int wave = tid >> 6, lane = tid & 63;
  const int j = blockIdx.x * 4 + wave;
  const float4* Dy4 = (const float4*)Dy;
  const float4* l4 = (const float4*)lna;
  float4 a = Dy4[(size_t)j * 64 + lane];
  float4 bq = l4[lane];
  float acc = a.x * bq.x + a.y * bq.y + a.z * bq.z + a.w * bq.w;
#pragma unroll
  for (int off = 32; off > 0; off >>= 1) acc += __shfl_down(acc, off);
  if (lane == 0) yout[j] = fmaxf(acc, 0.f) * fmaxf(x[j], 0.f);
}

// ---------------------------------------------------------------------------
// K4: u[d] += E[d][half] . y[half]   (2 blocks per d-row; 512 atomics total)
__global__ void k_u(const float* __restrict__ E, const float* __restrict__ y,
                    float* __restrict__ u) {
  __shared__ float red[256];
  const int d = blockIdx.x >> 1, hf = blockIdx.x & 1, tid = threadIdx.x;
  const float4* E4 = (const float4*)E;
  const float4* y4 = (const float4*)y;
  float acc = 0.f;
#pragma unroll
  for (int i = 0; i < 8; ++i) {
    int idx = hf * 2048 + tid + i * 256;
    float4 e = E4[(size_t)d * 4096 + idx];
    float4 yv = y4[idx];
    acc += e.x * yv.x + e.y * yv.y + e.z * yv.z + e.w * yv.w;
  }
  red[tid] = acc;
  __syncthreads();
  for (int off = 128; off > 0; off >>= 1) {
    if (tid < off) red[tid] += red[tid + off];
    __syncthreads();
  }
  if (tid == 0) atomicAdd(&u[d], red[0]);
}

// K5: v_star = ln_row(u)
__global__ void k_v(const float* __restrict__ u, float* __restrict__ vout) {
  __shared__ float red[256];
  const int d = threadIdx.x;
  float a = u[d];
  red[d] = a;
  __syncthreads();
  for (int off = 128; off > 0; off >>= 1) {
    if (d < off) red[d] += red[d + off];
    __syncthreads();
  }
  float m = red[0] * (1.f / 256.f);
  __syncthreads();
  float c0 = a - m;
  red[d] = c0 * c0;
  __syncthreads();
  for (int off = 128; off > 0; off >>= 1) {
    if (d < off) red[d] += red[d + off];
    __syncthreads();
  }
  float sd = sqrtf(red[0] * (1.f / 255.f));
  vout[d] = c0 / (sd + 1e-6f);
}

// ---------------------------------------------------------------------------
extern "C" void kernel_launch(void* const* d_in, const int* in_sizes, int n_in,
                              void* d_out, int out_size, void* d_ws, size_t ws_size,
                              hipStream_t stream) {
  const float* E = (const float*)d_in[0];     // [256][16384]
  const float* Dx = (const float*)d_in[1];    // [16384][256]
  const float* Dy = (const float*)d_in[2];    // [16384][256]
  const float* temb = (const float*)d_in[3];  // [32000][256]
  const int* toks = (const int*)d_in[4];      // [128]

  float* ws = (float*)d_ws;
  float* out = (float*)d_out;
  u16* cumVT = (u16*)(ws + WS_CUMVT);
  float* Vb  = ws + WS_VB;
  u16* VbBf  = (u16*)(ws + WS_VBBF);
  float* h   = ws + WS_H;
  float* u   = ws + WS_U;
  float* lna = ws + WS_LNA;

  float* xf  = out;                // x_{T-1}   [16384]
  float* yv  = out + Nn;           // ys[-1]    [16384]
  float* vs  = out + 2 * Nn;       // vs[-1]    [256]
  float* rho = out + 2 * Nn + Dd;  // rho_f     [256][16384]

  hipMemsetAsync(h, 0, (Tt + Dd) * sizeof(float), stream);  // h, u

  k_gather<<<Tt, Dd, 0, stream>>>(temb, toks, Vb, VbBf);
  k_cumv<<<1, Dd, 0, stream>>>(Vb, cumVT);
  k_p1<<<Nn / 32, 256, 0, stream>>>(Dx, VbBf, cumVT, h, xf, rho);
  k_astar<<<1, 256, 0, stream>>>(h, Vb, lna);
  k_y<<<Nn / 4, 256, 0, stream>>>(Dy, lna, xf, yv);
  k_u<<<2 * Dd, 256, 0, stream>>>(E, yv, u);
  k_v<<<1, 256, 0, stream>>>(u, vs);
}